// Round 12
// baseline (444.574 us; speedup 1.0000x reference)
//
#include <hip/hip_runtime.h>
#include <hip/hip_fp16.h>
#include <stdint.h>

#define B_ 32
#define S_ 1024
#define DM 256
#define H_ 8

typedef _Float16 f16;
typedef _Float16 f16x8 __attribute__((ext_vector_type(8)));
typedef _Float16 f16x4 __attribute__((ext_vector_type(4)));
typedef float f32x4 __attribute__((ext_vector_type(4)));

static __device__ __forceinline__ void gload16(const void* g, void* lds) {
  __builtin_amdgcn_global_load_lds(
      (const __attribute__((address_space(1))) void*)(uintptr_t)g,
      (__attribute__((address_space(3))) void*)(uintptr_t)lds, 16, 0, 0);
}
static __device__ __forceinline__ float ex2(float x) {
  float r; asm("v_exp_f32 %0, %1" : "=v"(r) : "v"(x)); return r;
}
static __device__ __forceinline__ unsigned pkrtz(float a, float b) {
  unsigned r; asm("v_cvt_pkrtz_f16_f32 %0, %1, %2" : "=v"(r) : "v"(a), "v"(b)); return r;
}
static __device__ __forceinline__ unsigned pkmul(unsigned a, unsigned b) {
  unsigned r; asm("v_pk_mul_f16 %0, %1, %2" : "=v"(r) : "v"(a), "v"(b)); return r;
}

// Merged prep: x->f16, 4 weights->f16 (contiguous dst), mask->packed f16-pair table.
__global__ __launch_bounds__(256) void prep_kernel(
    const float* __restrict__ x,
    const float* __restrict__ Wq, const float* __restrict__ Wk,
    const float* __restrict__ Wv, const float* __restrict__ Wo,
    const int* __restrict__ mask,
    f16* __restrict__ xh, f16* __restrict__ wh, unsigned* __restrict__ pmx) {
  int idx = blockIdx.x * 256 + threadIdx.x;
  if (idx < 2097152) {
    float4 v = reinterpret_cast<const float4*>(x)[idx];
    f16x4 h = {(f16)v.x, (f16)v.y, (f16)v.z, (f16)v.w};
    reinterpret_cast<f16x4*>(xh)[idx] = h;
  } else if (idx < 2097152 + 65536) {
    int j = idx - 2097152;
    const float* src = j < 16384 ? Wq : j < 32768 ? Wk : j < 49152 ? Wv : Wo;
    float4 v = reinterpret_cast<const float4*>(src)[j & 16383];
    f16x4 h = {(f16)v.x, (f16)v.y, (f16)v.z, (f16)v.w};
    reinterpret_cast<f16x4*>(wh)[j] = h;
  } else {
    int j = idx - (2097152 + 65536);
    int2 mm = reinterpret_cast<const int2*>(mask)[j];
    pmx[j] = (mm.x ? 0x3C00u : 0u) | (mm.y ? 0x3C000000u : 0u);
  }
}

// C = A @ W^T + b ; Q output pre-scaled by log2(e)/sqrt(32). 128x128 tile, 4 waves.
__global__ __launch_bounds__(256) void qkv_gemm_kernel(
    const f16* __restrict__ xh, const f16* __restrict__ wh,
    const float* __restrict__ bq, const float* __restrict__ bk, const float* __restrict__ bv,
    f16* __restrict__ qh, f16* __restrict__ kh, f16* __restrict__ vth) {
  __shared__ __align__(16) f16 Al[128 * 32];
  __shared__ __align__(16) f16 Bl[128 * 32];
  const int tid = threadIdx.x;
  const int w = tid >> 6, l = tid & 63;
  const int mt = blockIdx.x / 6, nt = blockIdx.x % 6;
  const int mbase = mt * 128, nbase = nt * 128;
  const int wm = w >> 1, wn = w & 1;
  const int lg = l >> 4, lr = l & 15;
  f32x4 acc[4][4] = {};
  for (int ks = 0; ks < 8; ++ks) {
    __syncthreads();
#pragma unroll
    for (int j = 0; j < 2; ++j) {
      int c = (j * 4 + w) * 64 + l;
      gload16(xh + (size_t)(mbase + (c >> 2)) * 256 + ks * 32 + (c & 3) * 8,
              (char*)Al + (j * 4 + w) * 1024);
      gload16(wh + (size_t)(nbase + (c >> 2)) * 256 + ks * 32 + (c & 3) * 8,
              (char*)Bl + (j * 4 + w) * 1024);
    }
    __syncthreads();
    f16x8 af[4], bf[4];
#pragma unroll
    for (int i = 0; i < 4; ++i)
      af[i] = *(const f16x8*)((const char*)Al + (wm * 64 + i * 16 + lr) * 64 + lg * 16);
#pragma unroll
    for (int i = 0; i < 4; ++i)
      bf[i] = *(const f16x8*)((const char*)Bl + (wn * 64 + i * 16 + lr) * 64 + lg * 16);
#pragma unroll
    for (int mi = 0; mi < 4; ++mi)
#pragma unroll
      for (int ni = 0; ni < 4; ++ni)
        acc[mi][ni] = __builtin_amdgcn_mfma_f32_16x16x32_f16(af[mi], bf[ni], acc[mi][ni], 0, 0, 0);
  }
  const int proj = nt >> 1;
  const float* bias = proj == 0 ? bq : (proj == 1 ? bk : bv);
  const float qsc = 0.25504182524668425f; // log2(e)/sqrt(32)
#pragma unroll
  for (int mi = 0; mi < 4; ++mi) {
#pragma unroll
    for (int ni = 0; ni < 4; ++ni) {
      int n = nbase + wn * 64 + ni * 16 + lr;
      float bb = bias[n & 255];
#pragma unroll
      for (int r = 0; r < 4; ++r) {
        int m = mbase + wm * 64 + mi * 16 + lg * 4 + r;
        float val = acc[mi][ni][r] + bb;
        if (proj == 0) val *= qsc;
        f16 hv = (f16)val;
        int b = m >> 10, s = m & 1023;
        int hh = (n >> 5) & 7, dd = n & 31;
        int bh = b * 8 + hh;
        if (proj == 0)      qh[((size_t)bh * 1024 + s) * 32 + dd] = hv;
        else if (proj == 1) kh[((size_t)bh * 1024 + s) * 32 + dd] = hv;
        else                vth[((size_t)bh * 32 + dd) * 1024 + s] = hv;
      }
    }
  }
}

// Flash attention v6: BARRIER-FREE. K/V fragments loaded global->VGPR directly
// (L2-resident; K double-buffered in regs, V+mask issued early). P via per-wave
// private LDS (v2's verified swizzled layout). No s_barrier, no manual waitcnt.
__global__ __launch_bounds__(256, 4) void attn_kernel(
    const f16* __restrict__ qh, const f16* __restrict__ kh, const f16* __restrict__ vth,
    const unsigned* __restrict__ pmx, f16* __restrict__ attnh) {
  __shared__ __align__(16) f16 Pl[4][16 * 64];   // 8 KB total, per-wave private
  const int tid = threadIdx.x;
  const int w = tid >> 6, l = tid & 63;
  // XCD swizzle: all 16 q-tiles of one bh land on one XCD (blockIdx%8 = XCD).
  const int dsp = blockIdx.x;
  const int slot = dsp >> 3;
  const int bh = (slot >> 4) * 8 + (dsp & 7);
  const int qt = slot & 15;
  const int qbase = qt * 64;
  const int lg = l >> 4, lr = l & 15;
  const int q = qbase + w * 16 + lr;   // lane's q-row (col side of swapped QK)

  f16x8 qf = *(const f16x8*)(qh + ((size_t)bh * 1024 + q) * 32 + lg * 8);
  const unsigned* mrow = pmx + (size_t)q * 512;
  const f16* kb = kh + (size_t)bh * 1024 * 32;    // K  [s][32]
  const f16* vb = vth + (size_t)bh * 32 * 1024;   // Vt [d][1024]

  float mrun = -1e30f;                 // per-ROW running max
  f32x4 oacc[2] = {};
  f32x4 lacc = {};
  const f32x4 zero = {};
  f16x8 ones;
#pragma unroll
  for (int i = 0; i < 8; ++i) ones[i] = (f16)1.0f;

  char* pbuf = (char*)Pl[w];

  f16x8 kf[2][4];
  // prologue: K fragments for tile 0
#pragma unroll
  for (int kt = 0; kt < 4; ++kt)
    kf[0][kt] = *(const f16x8*)(kb + (size_t)(kt * 16 + lr) * 32 + lg * 8);

#pragma unroll
  for (int t = 0; t < 16; ++t) {
    const int cur = t & 1, nxt = cur ^ 1;
    const int kvb = t * 64;
    // issue next-tile K early (register double-buffer; one full tile of flight)
    if (t < 15) {
#pragma unroll
      for (int kt = 0; kt < 4; ++kt)
        kf[nxt][kt] = *(const f16x8*)(kb + (size_t)(kvb + 64 + kt * 16 + lr) * 32 + lg * 8);
    }
    // V fragments + mask for this tile (used after softmax / in softmax -> latency covered)
    f16x8 vf[4];
#pragma unroll
    for (int ss = 0; ss < 2; ++ss)
#pragma unroll
      for (int dt = 0; dt < 2; ++dt)
        vf[ss * 2 + dt] = *(const f16x8*)(vb + (size_t)(dt * 16 + lr) * 1024 + kvb + ss * 32 + lg * 8);
    uint2 mc[4];
#pragma unroll
    for (int kt = 0; kt < 4; ++kt)
      mc[kt] = *(const uint2*)(mrow + t * 32 + kt * 8 + lg * 2);

    // QK^T swapped: D[row=kv_local][col=q]
    f32x4 sc[4];
    __builtin_amdgcn_s_setprio(1);
#pragma unroll
    for (int kt = 0; kt < 4; ++kt)
      sc[kt] = __builtin_amdgcn_mfma_f32_16x16x32_f16(kf[cur][kt], qf, zero, 0, 0, 0);
    __builtin_amdgcn_s_setprio(0);

    // per-row max over raw scores (upper bound; mask applied post-exp)
    float t0 = fmaxf(fmaxf(sc[0][0], sc[0][1]), fmaxf(sc[0][2], sc[0][3]));
    float t1 = fmaxf(fmaxf(sc[1][0], sc[1][1]), fmaxf(sc[1][2], sc[1][3]));
    float t2 = fmaxf(fmaxf(sc[2][0], sc[2][1]), fmaxf(sc[2][2], sc[2][3]));
    float t3 = fmaxf(fmaxf(sc[3][0], sc[3][1]), fmaxf(sc[3][2], sc[3][3]));
    float pmax = fmaxf(fmaxf(t0, t1), fmaxf(t2, t3));
    pmax = fmaxf(pmax, __shfl_xor(pmax, 16));
    pmax = fmaxf(pmax, __shfl_xor(pmax, 32));
    // deferred rescale (log2 domain; P bounded by 2^8)
    if (__any(pmax > mrun + 8.0f)) {
      float mnew = fmaxf(mrun, pmax);
      float alpha = ex2(mrun - mnew);
      mrun = mnew;
#pragma unroll
      for (int r = 0; r < 4; ++r) {
        float ar = __shfl(alpha, (l & 48) | (lg * 4 + r), 64);
        oacc[0][r] *= ar; oacc[1][r] *= ar; lacc[r] *= ar;
      }
    }
    // p = exp2(sc - m), pack, mask, write P (v2's verified XOR-swizzled layout)
#pragma unroll
    for (int kt = 0; kt < 4; ++kt) {
      float p0 = ex2(sc[kt][0] - mrun), p1 = ex2(sc[kt][1] - mrun);
      float p2 = ex2(sc[kt][2] - mrun), p3 = ex2(sc[kt][3] - mrun);
      unsigned lo = pkmul(pkrtz(p0, p1), mc[kt].x);
      unsigned hi = pkmul(pkrtz(p2, p3), mc[kt].y);
      *(uint64_t*)(pbuf + lr * 128 + ((kt * 32 + lg * 8) ^ ((lr & 7) << 4))) =
          (uint64_t)lo | ((uint64_t)hi << 32);
    }
    // PV + l accumulation (same-wave LDS roundtrip; compiler inserts lgkmcnt)
    __builtin_amdgcn_s_setprio(1);
#pragma unroll
    for (int ss = 0; ss < 2; ++ss) {
      f16x8 pa = *(const f16x8*)(pbuf + lr * 128 + ((ss * 64 + lg * 16) ^ ((lr & 7) << 4)));
      lacc = __builtin_amdgcn_mfma_f32_16x16x32_f16(pa, ones, lacc, 0, 0, 0);
#pragma unroll
      for (int dt = 0; dt < 2; ++dt)
        oacc[dt] = __builtin_amdgcn_mfma_f32_16x16x32_f16(pa, vf[ss * 2 + dt], oacc[dt], 0, 0, 0);
    }
    __builtin_amdgcn_s_setprio(0);
  }

  const int b = bh >> 3, hh = bh & 7;
#pragma unroll
  for (int r = 0; r < 4; ++r) {
    float inv = 1.0f / lacc[r];
    int qrow = qbase + w * 16 + lg * 4 + r;
    size_t rowoff = ((size_t)b * 1024 + qrow) * 256 + hh * 32;
    attnh[rowoff + lr]      = (f16)(oacc[0][r] * inv);
    attnh[rowoff + 16 + lr] = (f16)(oacc[1][r] * inv);
  }
}

__global__ __launch_bounds__(256) void out_gemm_kernel(
    const f16* __restrict__ ah, const f16* __restrict__ wh,
    const float* __restrict__ bo, float* __restrict__ out) {
  __shared__ __align__(16) f16 Al[128 * 32];
  __shared__ __align__(16) f16 Bl[128 * 32];
  const int tid = threadIdx.x;
  const int w = tid >> 6, l = tid & 63;
  const int mt = blockIdx.x >> 1, nt = blockIdx.x & 1;
  const int mbase = mt * 128, nbase = nt * 128;
  const int wm = w >> 1, wn = w & 1;
  const int lg = l >> 4, lr = l & 15;
  f32x4 acc[4][4] = {};
  for (int ks = 0; ks < 8; ++ks) {
    __syncthreads();
#pragma unroll
    for (int j = 0; j < 2; ++j) {
      int c = (j * 4 + w) * 64 + l;
      gload16(ah + (size_t)(mbase + (c >> 2)) * 256 + ks * 32 + (c & 3) * 8,
              (char*)Al + (j * 4 + w) * 1024);
      gload16(wh + (size_t)(nbase + (c >> 2)) * 256 + ks * 32 + (c & 3) * 8,
              (char*)Bl + (j * 4 + w) * 1024);
    }
    __syncthreads();
    f16x8 af[4], bf[4];
#pragma unroll
    for (int i = 0; i < 4; ++i)
      af[i] = *(const f16x8*)((const char*)Al + (wm * 64 + i * 16 + lr) * 64 + lg * 16);
#pragma unroll
    for (int i = 0; i < 4; ++i)
      bf[i] = *(const f16x8*)((const char*)Bl + (wn * 64 + i * 16 + lr) * 64 + lg * 16);
#pragma unroll
    for (int mi = 0; mi < 4; ++mi)
#pragma unroll
      for (int ni = 0; ni < 4; ++ni)
        acc[mi][ni] = __builtin_amdgcn_mfma_f32_16x16x32_f16(af[mi], bf[ni], acc[mi][ni], 0, 0, 0);
  }
#pragma unroll
  for (int mi = 0; mi < 4; ++mi) {
#pragma unroll
    for (int ni = 0; ni < 4; ++ni) {
      int n = nbase + wn * 64 + ni * 16 + lr;
      float bb = bo[n];
#pragma unroll
      for (int r = 0; r < 4; ++r) {
        int m = mbase + wm * 64 + mi * 16 + lg * 4 + r;
        out[(size_t)m * 256 + n] = acc[mi][ni][r] + bb;
      }
    }
  }
}

extern "C" void kernel_launch(void* const* d_in, const int* in_sizes, int n_in,
                              void* d_out, int out_size, void* d_ws, size_t ws_size,
                              hipStream_t stream) {
  const float* x  = (const float*)d_in[0];
  const int* mask = (const int*)d_in[1];
  const float* Wq = (const float*)d_in[2];
  const float* bq = (const float*)d_in[3];
  const float* Wk = (const float*)d_in[4];
  const float* bk = (const float*)d_in[5];
  const float* Wv = (const float*)d_in[6];
  const float* bv = (const float*)d_in[7];
  const float* Wo = (const float*)d_in[8];
  const float* bo = (const float*)d_in[9];
  float* out = (float*)d_out;
  char* ws = (char*)d_ws;

  f16* xh    = (f16*)(ws);                 // 16 MB (aliased by attnh after QKV GEMM)
  f16* attnh = (f16*)(ws);
  f16* qh    = (f16*)(ws + 16777216);
  f16* kh    = (f16*)(ws + 33554432);
  f16* vth   = (f16*)(ws + 50331648);      // V transposed [bh][32][1024]
  f16* wqkvh = (f16*)(ws + 67108864);      // [768][256] then Wo [256][256] contiguous
  f16* woh   = (f16*)(ws + 67502080);
  unsigned* pmx = (unsigned*)(ws + 67633152); // [1024][512] f16-pair mask table (2 MB)

  prep_kernel<<<10496, 256, 0, stream>>>(x, Wq, Wk, Wv, Wo, mask, xh, wqkvh, pmx);
  qkv_gemm_kernel<<<1536, 256, 0, stream>>>(xh, wqkvh, bq, bk, bv, qh, kh, vth);
  attn_kernel<<<4096, 256, 0, stream>>>(qh, kh, vth, pmx, attnh);
  out_gemm_kernel<<<512, 256, 0, stream>>>(attnh, woh, bo, out);
}